// Round 12
// baseline (232.127 us; speedup 1.0000x reference)
//
#include <hip/hip_runtime.h>
#include <stdint.h>

#define GRIDX 200
#define P 202                                   // padded grid dim
#define PCELL (P * P * P)                       // 8,242,408
#define GUARD 100000
#define NBITS (PCELL + GUARD)
#define NWP ((NBITS + 31) / 32)                 // 260,701 words
#define K_INV (PCELL + 50000)                   // guaranteed-miss key (guard center)
#define CIN 6
#define COUT 32
#define NOFF 27
#define BN_EPS 1e-5f
#define WPB 1024
#define NBLKP ((NWP + WPB - 1) / WPB)           // 255 (<=256 for single-block scan)

typedef __attribute__((ext_vector_type(8))) short short8;
typedef __attribute__((ext_vector_type(4))) float f32x4;

// ---------------- helpers ----------------

__device__ __forceinline__ int xcd_swizzle(int b, int nwg) {
    int q = nwg >> 3, r = nwg & 7;
    int xcd = b & 7, idx = b >> 3;
    int base = (xcd < r) ? xcd * (q + 1) : r * (q + 1) + (xcd - r) * q;
    return base + idx;
}

__device__ __forceinline__ unsigned short f2bf(float f) {
    uint32_t u = __float_as_uint(f);
    return (unsigned short)((u + 0x7FFFu + ((u >> 16) & 1u)) >> 16);   // RNE
}
__device__ __forceinline__ uint32_t pack2(float a, float b) {
    return (uint32_t)f2bf(a) | ((uint32_t)f2bf(b) << 16);
}

// ---------------- padded bitmap rank structure (uint2 = {word, base}) ----------------

__global__ void build_bitmap_p(const int* __restrict__ coords, int N,
                               uint2* __restrict__ recs) {
    int i = blockIdx.x * blockDim.x + threadIdx.x;
    if (i >= N) return;
    int x = coords[3 * i], y = coords[3 * i + 1], z = coords[3 * i + 2];
    int key = ((x + 1) * P + (y + 1)) * P + (z + 1);
    atomicOr((unsigned int*)&recs[key >> 5], 1u << (key & 31));
}

__global__ __launch_bounds__(256)
void bitmap_count_p(const uint2* __restrict__ recs, int* __restrict__ bcnt) {
    __shared__ int tot[256];
    int b = blockIdx.x, t = threadIdx.x;
    int w0 = b * WPB + t * 4;
    int s = 0;
#pragma unroll
    for (int j = 0; j < 4; j++) {
        int w = w0 + j;
        if (w < NWP) s += __popc(recs[w].x);
    }
    tot[t] = s;
    __syncthreads();
    if (t < 128) tot[t] += tot[t + 128];
    __syncthreads();
    if (t < 64) {
        int v = tot[t] + tot[t + 64];
#pragma unroll
        for (int d = 32; d > 0; d >>= 1) v += __shfl_down(v, d);
        if (t == 0) bcnt[b] = v;
    }
}

// exclusive scan of n<=256 values, one block of 256 threads
__global__ void scan_small(const int* __restrict__ cnt, int* __restrict__ base, int n) {
    __shared__ int tot[256];
    int t = threadIdx.x;
    int v = (t < n) ? cnt[t] : 0;
    tot[t] = v;
    __syncthreads();
    for (int d = 1; d < 256; d <<= 1) {
        int u = (t >= d) ? tot[t - d] : 0;
        __syncthreads();
        tot[t] += u;
        __syncthreads();
    }
    if (t < n) base[t] = tot[t] - v;     // exclusive
}

__global__ __launch_bounds__(256)
void base_fill_p(uint2* __restrict__ recs, const int* __restrict__ bbase) {
    __shared__ int tot[256];
    int b = blockIdx.x, t = threadIdx.x;
    int w0 = b * WPB + t * 4;
    int p[4];
    int s = 0;
#pragma unroll
    for (int j = 0; j < 4; j++) {
        int w = w0 + j;
        p[j] = (w < NWP) ? __popc(recs[w].x) : 0;
        s += p[j];
    }
    tot[t] = s;
    __syncthreads();
    for (int d = 1; d < 256; d <<= 1) {
        int u = (t >= d) ? tot[t - d] : 0;
        __syncthreads();
        tot[t] += u;
        __syncthreads();
    }
    int run = bbase[b] + tot[t] - s;     // exclusive global rank of first word
#pragma unroll
    for (int j = 0; j < 4; j++) {
        int w = w0 + j;
        if (w < NWP) recs[w].y = (uint32_t)run;
        run += p[j];
    }
}

// ---------------- rank scatter: original order -> sorted order ----------------

__global__ __launch_bounds__(256)
void rank_scatter_p(const int* __restrict__ coords, const float* __restrict__ feat, int N,
                    const uint2* __restrict__ recs,
                    int* __restrict__ sorig, int* __restrict__ skeys,
                    uint4* __restrict__ feat_bf) {
    int i = blockIdx.x * blockDim.x + threadIdx.x;
    if (i >= N) return;
    int x = coords[3 * i], y = coords[3 * i + 1], z = coords[3 * i + 2];
    int key = ((x + 1) * P + (y + 1)) * P + (z + 1);
    uint2 rb = recs[key >> 5];
    int bit = key & 31;
    int r = (int)(rb.y + (uint32_t)__popc(rb.x & ((1u << bit) - 1u)));
    sorig[r] = i;
    skeys[r] = key;
    const float* fr = feat + (size_t)i * CIN;
    float2 a = *(const float2*)fr;
    float2 bb = *(const float2*)(fr + 2);
    float2 cc = *(const float2*)(fr + 4);
    uint4 u;
    u.x = pack2(a.x, a.y);
    u.y = pack2(bb.x, bb.y);
    u.z = pack2(cc.x, cc.y);
    u.w = 0u;
    feat_bf[r] = u;
}

// ---------------- W fragment prep (once) ----------------
// K-packing: k = koff*8 + ci (ci<6 real, ci=6,7 zero; koff>=27 zero).
// B-fragment (16x16x32 bf16): lane l holds B[k = ks*32+(l>>4)*8+b][col = nt*16+(l&15)]

__global__ void prep_wfrag(const float* __restrict__ W, uint4* __restrict__ wfrag) {
    int idx = blockIdx.x * blockDim.x + threadIdx.x;
    if (idx >= 7 * 2 * 64) return;
    int l = idx & 63;
    int nt = (idx >> 6) & 1;
    int ks = idx >> 7;
    int koff = ks * 4 + (l >> 4);
    int col = nt * 16 + (l & 15);
    unsigned short v[8];
#pragma unroll
    for (int ci = 0; ci < 8; ci++) {
        float f = 0.f;
        if (ci < CIN && koff < NOFF) f = W[(koff * CIN + ci) * COUT + col];
        v[ci] = f2bf(f);
    }
    uint4 u;
    u.x = (uint32_t)v[0] | ((uint32_t)v[1] << 16);
    u.y = (uint32_t)v[2] | ((uint32_t)v[3] << 16);
    u.z = (uint32_t)v[4] | ((uint32_t)v[5] << 16);
    u.w = (uint32_t)v[6] | ((uint32_t)v[7] << 16);
    wfrag[idx] = u;
}

// ---------------- conv: multi-site-block, predicated gathers, fused stats ----------------
// Grid 2048 = 8 blocks/CU x 4 waves = 32 waves/CU (full wave slots).
// Clds double-buffered -> ONE barrier per site-block iteration: write buf[i&1],
// barrier, read buf[i&1]; the next write to the same buffer is 2 iterations
// (hence >=1 barrier) later, so the single barrier orders both hazards.

__global__ __launch_bounds__(256, 4)
void conv_mfma(const uint4* __restrict__ feat_bf,
               const int* __restrict__ skeys,
               const int* __restrict__ sorig,
               const uint4* __restrict__ wfrag,
               const uint2* __restrict__ recs, int N, int nsb,
               float* __restrict__ out,
               float* __restrict__ stats_g) {
    __shared__ __align__(16) float Clds[2][64 * 36];   // 18432 B
    __shared__ float bstat[64];

    int tid = threadIdx.x;
    int w = tid >> 6, l = tid & 63;
    int col = l & 15;
    int rg = l >> 4;
    int kb = rg;

    if (tid < 64) bstat[tid] = 0.f;

    // B fragments: loaded ONCE per block
    const short8* wf8 = (const short8*)wfrag;
    short8 bf0[7], bf1[7];
#pragma unroll
    for (int ks = 0; ks < 7; ks++) {
        bf0[ks] = wf8[(ks * 2 + 0) * 64 + l];
        bf1[ks] = wf8[(ks * 2 + 1) * 64 + l];
    }

    // key deltas: computed ONCE (koff = ks*4 + kb)
    int dlt[7];
    bool pad[7];
#pragma unroll
    for (int ks = 0; ks < 7; ks++) {
        int koff = ks * 4 + kb;
        pad[ks] = (koff >= NOFF);
        int t9 = koff / 9;
        int r9 = koff - t9 * 9;
        int t3 = r9 / 3;
        dlt[ks] = (t9 - 1) * (P * P) + (t3 - 1) * P + (r9 - t3 * 3 - 1);
    }

    const uint4* fb16 = (const uint4*)feat_bf;

    float as0 = 0.f, aq0 = 0.f, as1 = 0.f, aq1 = 0.f;
    int it = 0;

    for (int sb = blockIdx.x; sb < nsb; sb += gridDim.x, it++) {
        int b = xcd_swizzle(sb, nsb);
        int bs = b * 64;
        int site = bs + w * 16 + col;
        int key = (site < N) ? skeys[site] : K_INV;

        // rank probes + PREDICATED gathers
        short8 av[7];
#pragma unroll
        for (int ks = 0; ks < 7; ks++) {
            int nkey = pad[ks] ? K_INV : key + dlt[ks];
            uint2 rb = recs[nkey >> 5];
            int bit = nkey & 31;
            bool hit = (rb.x >> bit) & 1u;
            uint4 a4 = make_uint4(0u, 0u, 0u, 0u);
            if (hit) {
                int pos = (int)(rb.y + (uint32_t)__popc(rb.x & ((1u << bit) - 1u)));
                a4 = fb16[pos];
            }
            av[ks] = *(const short8*)&a4;
        }

        f32x4 acc0 = {0.f, 0.f, 0.f, 0.f};
        f32x4 acc1 = {0.f, 0.f, 0.f, 0.f};
#pragma unroll
        for (int ks = 0; ks < 7; ks++) {
            acc0 = __builtin_amdgcn_mfma_f32_16x16x32_bf16(av[ks], bf0[ks], acc0, 0, 0, 0);
            acc1 = __builtin_amdgcn_mfma_f32_16x16x32_bf16(av[ks], bf1[ks], acc1, 0, 0, 0);
        }

        as0 += acc0[0] + acc0[1] + acc0[2] + acc0[3];
        aq0 += acc0[0]*acc0[0] + acc0[1]*acc0[1] + acc0[2]*acc0[2] + acc0[3]*acc0[3];
        as1 += acc1[0] + acc1[1] + acc1[2] + acc1[3];
        aq1 += acc1[0]*acc1[0] + acc1[1]*acc1[1] + acc1[2]*acc1[2] + acc1[3]*acc1[3];

        float* Cb = Clds[it & 1];
#pragma unroll
        for (int r = 0; r < 4; r++) {
            int s = w * 16 + rg * 4 + r; // C/D map: col=lane&15, row=(lane>>4)*4+r
            Cb[s * 36 + col] = acc0[r];
            Cb[s * 36 + col + 16] = acc1[r];
        }
        __syncthreads();                 // single barrier: orders write->read (this buf)
                                         // and read(prev iter)->write(next use of this buf)

        int st = tid >> 2;               // site-local 0..63
        int q = (tid & 3) * 2;           // chunk pair
        int sr = bs + st;
        if (sr < N) {
            float4* gp = (float4*)(out + (size_t)sorig[sr] * COUT + q * 4);
            gp[0] = *(const float4*)&Cb[st * 36 + q * 4];
            gp[1] = *(const float4*)&Cb[st * 36 + q * 4 + 4];
        }
    }

    // final stats reduction (once per block)
    as0 += __shfl_xor(as0, 16); as0 += __shfl_xor(as0, 32);
    aq0 += __shfl_xor(aq0, 16); aq0 += __shfl_xor(aq0, 32);
    as1 += __shfl_xor(as1, 16); as1 += __shfl_xor(as1, 32);
    aq1 += __shfl_xor(aq1, 16); aq1 += __shfl_xor(aq1, 32);
    __syncthreads();
    if (l < 16) {
        atomicAdd(&bstat[col], as0);
        atomicAdd(&bstat[16 + col], as1);
        atomicAdd(&bstat[32 + col], aq0);
        atomicAdd(&bstat[48 + col], aq1);
    }
    __syncthreads();
    if (tid < 64) {
        int slice = blockIdx.x & 63;
        atomicAdd(&stats_g[slice * 64 + tid], bstat[tid]);
    }
}

// ---------------- BN finalize / norm ----------------

__global__ void finalize_sliced(const float* __restrict__ stats_g,
                                const float* __restrict__ gamma,
                                const float* __restrict__ beta,
                                float invN, float* __restrict__ scsh) {
    int c = threadIdx.x;
    if (c < COUT) {
        float s = 0.f, q = 0.f;
        for (int sl = 0; sl < 64; sl++) {
            s += stats_g[sl * 64 + c];
            q += stats_g[sl * 64 + 32 + c];
        }
        float mean = s * invN;
        float var = q * invN - mean * mean;
        float sc = gamma[c] * rsqrtf(var + BN_EPS);
        scsh[c] = sc;
        scsh[COUT + c] = beta[c] - mean * sc;
    }
}

__global__ __launch_bounds__(256)
void norm_kernel(float* __restrict__ out, long total_vec,
                 const float* __restrict__ scaleshift) {
    __shared__ float sc[COUT], sh[COUT];
    for (int t = threadIdx.x; t < COUT; t += blockDim.x) {
        sc[t] = scaleshift[t];
        sh[t] = scaleshift[COUT + t];
    }
    __syncthreads();
    long stride = (long)gridDim.x * blockDim.x;
    float4* p = (float4*)out;
    for (long v = (long)blockIdx.x * blockDim.x + threadIdx.x; v < total_vec; v += stride) {
        int cbase = (int)(v & 7) * 4;
        float4 u = p[v];
        u.x = fmaxf(u.x * sc[cbase + 0] + sh[cbase + 0], 0.f);
        u.y = fmaxf(u.y * sc[cbase + 1] + sh[cbase + 1], 0.f);
        u.z = fmaxf(u.z * sc[cbase + 2] + sh[cbase + 2], 0.f);
        u.w = fmaxf(u.w * sc[cbase + 3] + sh[cbase + 3], 0.f);
        p[v] = u;
    }
}

// ---------------- launch ----------------

extern "C" void kernel_launch(void* const* d_in, const int* in_sizes, int n_in,
                              void* d_out, int out_size, void* d_ws, size_t ws_size,
                              hipStream_t stream) {
    const float* feat   = (const float*)d_in[0];
    const int*   coords = (const int*)d_in[1];
    const float* W      = (const float*)d_in[2];
    const float* gamma  = (const float*)d_in[3];
    const float* beta   = (const float*)d_in[4];
    float* out = (float*)d_out;

    int N = in_sizes[0] / CIN;
    const int threads = 256;
    int blocksN = (N + threads - 1) / threads;
    int nsb = (N + 63) / 64;
    int cblocks = 2048;                  // 8 blocks/CU -> 32 waves/CU (full)
    long total_vec = (long)N * COUT / 4;

    size_t a256 = 255;
    size_t recs_b     = (size_t)NWP * 8;                       // ~2.1 MB
    size_t off_skeys  = (recs_b + a256) & ~a256;
    size_t off_featbf = (off_skeys + (size_t)N * 4 + a256) & ~a256;
    size_t off_sorig  = (off_featbf + (size_t)(N + 1) * 16 + a256) & ~a256;
    size_t off_bcnt   = (off_sorig + (size_t)N * 4 + a256) & ~a256;
    size_t off_bbase  = (off_bcnt + 256 * 4 + a256) & ~a256;
    size_t off_wfrag  = (off_bbase + 256 * 4 + a256) & ~a256;
    size_t off_stats  = (off_wfrag + (size_t)(7 * 2 * 64) * 16 + a256) & ~a256;
    size_t off_scsh   = off_stats + (size_t)64 * 64 * 4;

    uint2* recs  = (uint2*)d_ws;
    int*   skeys = (int*)((char*)d_ws + off_skeys);
    uint4* featb = (uint4*)((char*)d_ws + off_featbf);
    int*   sorig = (int*)((char*)d_ws + off_sorig);
    int*   bcnt  = (int*)((char*)d_ws + off_bcnt);
    int*   bbase = (int*)((char*)d_ws + off_bbase);
    uint4* wfrag = (uint4*)((char*)d_ws + off_wfrag);
    float* stats = (float*)((char*)d_ws + off_stats);
    float* scsh  = (float*)((char*)d_ws + off_scsh);

    hipMemsetAsync(recs, 0, recs_b, stream);
    hipMemsetAsync(stats, 0, (size_t)64 * 64 * 4, stream);
    prep_wfrag<<<4, threads, 0, stream>>>(W, wfrag);
    build_bitmap_p<<<blocksN, threads, 0, stream>>>(coords, N, recs);
    bitmap_count_p<<<NBLKP, threads, 0, stream>>>(recs, bcnt);
    scan_small<<<1, threads, 0, stream>>>(bcnt, bbase, NBLKP);
    base_fill_p<<<NBLKP, threads, 0, stream>>>(recs, bbase);
    rank_scatter_p<<<blocksN, threads, 0, stream>>>(coords, feat, N, recs, sorig, skeys, featb);
    conv_mfma<<<cblocks, threads, 0, stream>>>(featb, skeys, sorig, wfrag, recs, N, nsb, out, stats);
    finalize_sliced<<<1, 64, 0, stream>>>(stats, gamma, beta, 1.0f / (float)N, scsh);
    norm_kernel<<<2048, threads, 0, stream>>>(out, total_vec, scsh);
}

// Round 13
// 217.093 us; speedup vs baseline: 1.0693x; 1.0693x over previous
//
#include <hip/hip_runtime.h>
#include <stdint.h>

#define GRIDX 200
#define P 202                                   // padded grid dim
#define PCELL (P * P * P)                       // 8,242,408
#define GUARD 100000
#define NBITS (PCELL + GUARD)
#define NWP ((NBITS + 31) / 32)                 // 260,701 words
#define K_INV (PCELL + 50000)                   // guaranteed-miss key (guard center)
#define CIN 6
#define COUT 32
#define NOFF 27
#define BN_EPS 1e-5f
#define WPB 1024
#define NBLKP ((NWP + WPB - 1) / WPB)           // 255 (<=256 for single-block scan)

typedef __attribute__((ext_vector_type(8))) short short8;
typedef __attribute__((ext_vector_type(4))) float f32x4;

// ---------------- helpers ----------------

__device__ __forceinline__ int xcd_swizzle(int b, int nwg) {
    int q = nwg >> 3, r = nwg & 7;
    int xcd = b & 7, idx = b >> 3;
    int base = (xcd < r) ? xcd * (q + 1) : r * (q + 1) + (xcd - r) * q;
    return base + idx;
}

__device__ __forceinline__ unsigned short f2bf(float f) {
    uint32_t u = __float_as_uint(f);
    return (unsigned short)((u + 0x7FFFu + ((u >> 16) & 1u)) >> 16);   // RNE
}
__device__ __forceinline__ uint32_t pack2(float a, float b) {
    return (uint32_t)f2bf(a) | ((uint32_t)f2bf(b) << 16);
}

// ---------------- padded bitmap rank structure (uint2 = {word, base}) ----------------

__global__ void build_bitmap_p(const int* __restrict__ coords, int N,
                               uint2* __restrict__ recs) {
    int i = blockIdx.x * blockDim.x + threadIdx.x;
    if (i >= N) return;
    int x = coords[3 * i], y = coords[3 * i + 1], z = coords[3 * i + 2];
    int key = ((x + 1) * P + (y + 1)) * P + (z + 1);
    atomicOr((unsigned int*)&recs[key >> 5], 1u << (key & 31));
}

__global__ __launch_bounds__(256)
void bitmap_count_p(const uint2* __restrict__ recs, int* __restrict__ bcnt) {
    __shared__ int tot[256];
    int b = blockIdx.x, t = threadIdx.x;
    int w0 = b * WPB + t * 4;
    int s = 0;
#pragma unroll
    for (int j = 0; j < 4; j++) {
        int w = w0 + j;
        if (w < NWP) s += __popc(recs[w].x);
    }
    tot[t] = s;
    __syncthreads();
    if (t < 128) tot[t] += tot[t + 128];
    __syncthreads();
    if (t < 64) {
        int v = tot[t] + tot[t + 64];
#pragma unroll
        for (int d = 32; d > 0; d >>= 1) v += __shfl_down(v, d);
        if (t == 0) bcnt[b] = v;
    }
}

// exclusive scan of n<=256 values, one block of 256 threads
__global__ void scan_small(const int* __restrict__ cnt, int* __restrict__ base, int n) {
    __shared__ int tot[256];
    int t = threadIdx.x;
    int v = (t < n) ? cnt[t] : 0;
    tot[t] = v;
    __syncthreads();
    for (int d = 1; d < 256; d <<= 1) {
        int u = (t >= d) ? tot[t - d] : 0;
        __syncthreads();
        tot[t] += u;
        __syncthreads();
    }
    if (t < n) base[t] = tot[t] - v;     // exclusive
}

__global__ __launch_bounds__(256)
void base_fill_p(uint2* __restrict__ recs, const int* __restrict__ bbase) {
    __shared__ int tot[256];
    int b = blockIdx.x, t = threadIdx.x;
    int w0 = b * WPB + t * 4;
    int p[4];
    int s = 0;
#pragma unroll
    for (int j = 0; j < 4; j++) {
        int w = w0 + j;
        p[j] = (w < NWP) ? __popc(recs[w].x) : 0;
        s += p[j];
    }
    tot[t] = s;
    __syncthreads();
    for (int d = 1; d < 256; d <<= 1) {
        int u = (t >= d) ? tot[t - d] : 0;
        __syncthreads();
        tot[t] += u;
        __syncthreads();
    }
    int run = bbase[b] + tot[t] - s;     // exclusive global rank of first word
#pragma unroll
    for (int j = 0; j < 4; j++) {
        int w = w0 + j;
        if (w < NWP) recs[w].y = (uint32_t)run;
        run += p[j];
    }
}

// ---------------- skeys generated COALESCED from the bitmap (sorted order) ----------------
// skeys[r] is a pure function of the bitmap: consecutive threads emit adjacent
// runs at recs[w].base -> fully sequential 4 MB write (replaces a scattered store).

__global__ __launch_bounds__(256)
void gen_skeys(const uint2* __restrict__ recs, int* __restrict__ skeys) {
    int w = blockIdx.x * blockDim.x + threadIdx.x;
    if (w >= NWP) return;
    uint2 rb = recs[w];
    uint32_t m = rb.x;
    int base = (int)rb.y;
    int key0 = w * 32;
    while (m) {
        int bit = __ffs((int)m) - 1;
        skeys[base++] = key0 + bit;
        m &= m - 1u;
    }
}

// ---------------- rank scatter: original order -> sorted order ----------------

__global__ __launch_bounds__(256)
void rank_scatter_p(const int* __restrict__ coords, const float* __restrict__ feat, int N,
                    const uint2* __restrict__ recs,
                    int* __restrict__ sorig,
                    uint4* __restrict__ feat_bf) {
    int i = blockIdx.x * blockDim.x + threadIdx.x;
    if (i >= N) return;
    int x = coords[3 * i], y = coords[3 * i + 1], z = coords[3 * i + 2];
    int key = ((x + 1) * P + (y + 1)) * P + (z + 1);
    uint2 rb = recs[key >> 5];
    int bit = key & 31;
    int r = (int)(rb.y + (uint32_t)__popc(rb.x & ((1u << bit) - 1u)));
    sorig[r] = i;
    const float* fr = feat + (size_t)i * CIN;
    float2 a = *(const float2*)fr;
    float2 bb = *(const float2*)(fr + 2);
    float2 cc = *(const float2*)(fr + 4);
    uint4 u;
    u.x = pack2(a.x, a.y);
    u.y = pack2(bb.x, bb.y);
    u.z = pack2(cc.x, cc.y);
    u.w = 0u;
    feat_bf[r] = u;
}

// ---------------- W fragment prep (once) ----------------
// K-packing: k = koff*8 + ci (ci<6 real, ci=6,7 zero; koff>=27 zero).
// B-fragment (16x16x32 bf16): lane l holds B[k = ks*32+(l>>4)*8+b][col = nt*16+(l&15)]

__global__ void prep_wfrag(const float* __restrict__ W, uint4* __restrict__ wfrag) {
    int idx = blockIdx.x * blockDim.x + threadIdx.x;
    if (idx >= 7 * 2 * 64) return;
    int l = idx & 63;
    int nt = (idx >> 6) & 1;
    int ks = idx >> 7;
    int koff = ks * 4 + (l >> 4);
    int col = nt * 16 + (l & 15);
    unsigned short v[8];
#pragma unroll
    for (int ci = 0; ci < 8; ci++) {
        float f = 0.f;
        if (ci < CIN && koff < NOFF) f = W[(koff * CIN + ci) * COUT + col];
        v[ci] = f2bf(f);
    }
    uint4 u;
    u.x = (uint32_t)v[0] | ((uint32_t)v[1] << 16);
    u.y = (uint32_t)v[2] | ((uint32_t)v[3] << 16);
    u.z = (uint32_t)v[4] | ((uint32_t)v[5] << 16);
    u.w = (uint32_t)v[6] | ((uint32_t)v[7] << 16);
    wfrag[idx] = u;
}

// ---------------- conv: R11 config (empirical optimum, 77 us) ----------------
// 1024 blocks grid-stride; single Clds buffer; two barriers/iter; predicated
// gathers; B-frags + key deltas hoisted out of the site-block loop.

__global__ __launch_bounds__(256, 4)
void conv_mfma(const uint4* __restrict__ feat_bf,
               const int* __restrict__ skeys,
               const int* __restrict__ sorig,
               const uint4* __restrict__ wfrag,
               const uint2* __restrict__ recs, int N, int nsb,
               float* __restrict__ out,
               float* __restrict__ stats_g) {
    __shared__ __align__(16) float Clds[64 * 36];    // 9216 B
    __shared__ float bstat[64];

    int tid = threadIdx.x;
    int w = tid >> 6, l = tid & 63;
    int col = l & 15;
    int rg = l >> 4;
    int kb = rg;

    if (tid < 64) bstat[tid] = 0.f;

    // B fragments: loaded ONCE per block (amortized over ~15 site-blocks)
    const short8* wf8 = (const short8*)wfrag;
    short8 bf0[7], bf1[7];
#pragma unroll
    for (int ks = 0; ks < 7; ks++) {
        bf0[ks] = wf8[(ks * 2 + 0) * 64 + l];
        bf1[ks] = wf8[(ks * 2 + 1) * 64 + l];
    }

    // key deltas: computed ONCE (koff = ks*4 + kb); pad slot handled via miss key
    int dlt[7];
    bool pad[7];
#pragma unroll
    for (int ks = 0; ks < 7; ks++) {
        int koff = ks * 4 + kb;
        pad[ks] = (koff >= NOFF);
        int t9 = koff / 9;
        int r9 = koff - t9 * 9;
        int t3 = r9 / 3;
        dlt[ks] = (t9 - 1) * (P * P) + (t3 - 1) * P + (r9 - t3 * 3 - 1);
    }

    const uint4* fb16 = (const uint4*)feat_bf;

    float as0 = 0.f, aq0 = 0.f, as1 = 0.f, aq1 = 0.f;

    for (int sb = blockIdx.x; sb < nsb; sb += gridDim.x) {
        int b = xcd_swizzle(sb, nsb);
        int bs = b * 64;
        int site = bs + w * 16 + col;
        int key = (site < N) ? skeys[site] : K_INV;

        // rank probes + PREDICATED gathers (miss lanes issue no address)
        short8 av[7];
#pragma unroll
        for (int ks = 0; ks < 7; ks++) {
            int nkey = pad[ks] ? K_INV : key + dlt[ks];
            uint2 rb = recs[nkey >> 5];
            int bit = nkey & 31;
            bool hit = (rb.x >> bit) & 1u;
            uint4 a4 = make_uint4(0u, 0u, 0u, 0u);
            if (hit) {
                int pos = (int)(rb.y + (uint32_t)__popc(rb.x & ((1u << bit) - 1u)));
                a4 = fb16[pos];
            }
            av[ks] = *(const short8*)&a4;
        }

        f32x4 acc0 = {0.f, 0.f, 0.f, 0.f};
        f32x4 acc1 = {0.f, 0.f, 0.f, 0.f};
#pragma unroll
        for (int ks = 0; ks < 7; ks++) {
            acc0 = __builtin_amdgcn_mfma_f32_16x16x32_bf16(av[ks], bf0[ks], acc0, 0, 0, 0);
            acc1 = __builtin_amdgcn_mfma_f32_16x16x32_bf16(av[ks], bf1[ks], acc1, 0, 0, 0);
        }

        // accumulate stats (invalid sites contribute exact zeros)
        as0 += acc0[0] + acc0[1] + acc0[2] + acc0[3];
        aq0 += acc0[0]*acc0[0] + acc0[1]*acc0[1] + acc0[2]*acc0[2] + acc0[3]*acc0[3];
        as1 += acc1[0] + acc1[1] + acc1[2] + acc1[3];
        aq1 += acc1[0]*acc1[0] + acc1[1]*acc1[1] + acc1[2]*acc1[2] + acc1[3]*acc1[3];

        __syncthreads();                 // prev iteration's Clds reads complete
#pragma unroll
        for (int r = 0; r < 4; r++) {
            int s = w * 16 + rg * 4 + r; // C/D map: col=lane&15, row=(lane>>4)*4+r
            Clds[s * 36 + col] = acc0[r];
            Clds[s * 36 + col + 16] = acc1[r];
        }
        __syncthreads();                 // Clds writes complete

        int st = tid >> 2;               // site-local 0..63
        int q = (tid & 3) * 2;           // chunk pair
        int sr = bs + st;
        if (sr < N) {
            float4* gp = (float4*)(out + (size_t)sorig[sr] * COUT + q * 4);
            gp[0] = *(const float4*)&Clds[st * 36 + q * 4];
            gp[1] = *(const float4*)&Clds[st * 36 + q * 4 + 4];
        }
    }

    // final stats reduction (once per block)
    as0 += __shfl_xor(as0, 16); as0 += __shfl_xor(as0, 32);
    aq0 += __shfl_xor(aq0, 16); aq0 += __shfl_xor(aq0, 32);
    as1 += __shfl_xor(as1, 16); as1 += __shfl_xor(as1, 32);
    aq1 += __shfl_xor(aq1, 16); aq1 += __shfl_xor(aq1, 32);
    __syncthreads();
    if (l < 16) {
        atomicAdd(&bstat[col], as0);
        atomicAdd(&bstat[16 + col], as1);
        atomicAdd(&bstat[32 + col], aq0);
        atomicAdd(&bstat[48 + col], aq1);
    }
    __syncthreads();
    if (tid < 64) {
        int slice = blockIdx.x & 63;
        atomicAdd(&stats_g[slice * 64 + tid], bstat[tid]);
    }
}

// ---------------- BN finalize / norm ----------------

__global__ void finalize_sliced(const float* __restrict__ stats_g,
                                const float* __restrict__ gamma,
                                const float* __restrict__ beta,
                                float invN, float* __restrict__ scsh) {
    int c = threadIdx.x;
    if (c < COUT) {
        float s = 0.f, q = 0.f;
        for (int sl = 0; sl < 64; sl++) {
            s += stats_g[sl * 64 + c];
            q += stats_g[sl * 64 + 32 + c];
        }
        float mean = s * invN;
        float var = q * invN - mean * mean;
        float sc = gamma[c] * rsqrtf(var + BN_EPS);
        scsh[c] = sc;
        scsh[COUT + c] = beta[c] - mean * sc;
    }
}

__global__ __launch_bounds__(256)
void norm_kernel(float* __restrict__ out, long total_vec,
                 const float* __restrict__ scaleshift) {
    __shared__ float sc[COUT], sh[COUT];
    for (int t = threadIdx.x; t < COUT; t += blockDim.x) {
        sc[t] = scaleshift[t];
        sh[t] = scaleshift[COUT + t];
    }
    __syncthreads();
    long stride = (long)gridDim.x * blockDim.x;
    float4* p = (float4*)out;
    for (long v = (long)blockIdx.x * blockDim.x + threadIdx.x; v < total_vec; v += stride) {
        int cbase = (int)(v & 7) * 4;
        float4 u = p[v];
        u.x = fmaxf(u.x * sc[cbase + 0] + sh[cbase + 0], 0.f);
        u.y = fmaxf(u.y * sc[cbase + 1] + sh[cbase + 1], 0.f);
        u.z = fmaxf(u.z * sc[cbase + 2] + sh[cbase + 2], 0.f);
        u.w = fmaxf(u.w * sc[cbase + 3] + sh[cbase + 3], 0.f);
        p[v] = u;
    }
}

// ---------------- launch ----------------

extern "C" void kernel_launch(void* const* d_in, const int* in_sizes, int n_in,
                              void* d_out, int out_size, void* d_ws, size_t ws_size,
                              hipStream_t stream) {
    const float* feat   = (const float*)d_in[0];
    const int*   coords = (const int*)d_in[1];
    const float* W      = (const float*)d_in[2];
    const float* gamma  = (const float*)d_in[3];
    const float* beta   = (const float*)d_in[4];
    float* out = (float*)d_out;

    int N = in_sizes[0] / CIN;
    const int threads = 256;
    int blocksN = (N + threads - 1) / threads;
    int nsb = (N + 63) / 64;
    int cblocks = 1024;                  // R11 empirical optimum
    long total_vec = (long)N * COUT / 4;

    size_t a256 = 255;
    size_t recs_b     = (size_t)NWP * 8;                       // ~2.1 MB
    size_t off_skeys  = (recs_b + a256) & ~a256;
    size_t off_featbf = (off_skeys + (size_t)N * 4 + a256) & ~a256;
    size_t off_sorig  = (off_featbf + (size_t)(N + 1) * 16 + a256) & ~a256;
    size_t off_bcnt   = (off_sorig + (size_t)N * 4 + a256) & ~a256;
    size_t off_bbase  = (off_bcnt + 256 * 4 + a256) & ~a256;
    size_t off_wfrag  = (off_bbase + 256 * 4 + a256) & ~a256;
    size_t off_stats  = (off_wfrag + (size_t)(7 * 2 * 64) * 16 + a256) & ~a256;
    size_t off_scsh   = off_stats + (size_t)64 * 64 * 4;

    uint2* recs  = (uint2*)d_ws;
    int*   skeys = (int*)((char*)d_ws + off_skeys);
    uint4* featb = (uint4*)((char*)d_ws + off_featbf);
    int*   sorig = (int*)((char*)d_ws + off_sorig);
    int*   bcnt  = (int*)((char*)d_ws + off_bcnt);
    int*   bbase = (int*)((char*)d_ws + off_bbase);
    uint4* wfrag = (uint4*)((char*)d_ws + off_wfrag);
    float* stats = (float*)((char*)d_ws + off_stats);
    float* scsh  = (float*)((char*)d_ws + off_scsh);

    hipMemsetAsync(recs, 0, recs_b, stream);
    hipMemsetAsync(stats, 0, (size_t)64 * 64 * 4, stream);
    prep_wfrag<<<4, threads, 0, stream>>>(W, wfrag);
    build_bitmap_p<<<blocksN, threads, 0, stream>>>(coords, N, recs);
    bitmap_count_p<<<NBLKP, threads, 0, stream>>>(recs, bcnt);
    scan_small<<<1, threads, 0, stream>>>(bcnt, bbase, NBLKP);
    base_fill_p<<<NBLKP, threads, 0, stream>>>(recs, bbase);
    gen_skeys<<<(NWP + threads - 1) / threads, threads, 0, stream>>>(recs, skeys);
    rank_scatter_p<<<blocksN, threads, 0, stream>>>(coords, feat, N, recs, sorig, featb);
    conv_mfma<<<cblocks, threads, 0, stream>>>(featb, skeys, sorig, wfrag, recs, N, nsb, out, stats);
    finalize_sliced<<<1, 64, 0, stream>>>(stats, gamma, beta, 1.0f / (float)N, scsh);
    norm_kernel<<<2048, threads, 0, stream>>>(out, total_vec, scsh);
}

// Round 14
// 195.897 us; speedup vs baseline: 1.1849x; 1.1082x over previous
//
#include <hip/hip_runtime.h>
#include <stdint.h>

#define GRIDX 200
#define P 202                                   // padded grid dim
#define PCELL (P * P * P)                       // 8,242,408
#define GUARD 100000
#define NBITS (PCELL + GUARD)
#define NWP ((NBITS + 31) / 32)                 // 260,701 words
#define K_INV (PCELL + 50000)                   // guaranteed-miss key (guard center)
#define CIN 6
#define COUT 32
#define NOFF 27
#define BN_EPS 1e-5f
#define WPB 1024
#define NBLKP ((NWP + WPB - 1) / WPB)           // 255 (<=256 for single-block scan)

typedef __attribute__((ext_vector_type(8))) short short8;
typedef __attribute__((ext_vector_type(4))) float f32x4;

// ---------------- helpers ----------------

__device__ __forceinline__ int xcd_swizzle(int b, int nwg) {
    int q = nwg >> 3, r = nwg & 7;
    int xcd = b & 7, idx = b >> 3;
    int base = (xcd < r) ? xcd * (q + 1) : r * (q + 1) + (xcd - r) * q;
    return base + idx;
}

__device__ __forceinline__ unsigned short f2bf(float f) {
    uint32_t u = __float_as_uint(f);
    return (unsigned short)((u + 0x7FFFu + ((u >> 16) & 1u)) >> 16);   // RNE
}
__device__ __forceinline__ uint32_t pack2(float a, float b) {
    return (uint32_t)f2bf(a) | ((uint32_t)f2bf(b) << 16);
}

// padded-grid key delta for kernel offset koff (0..26)
__device__ __forceinline__ int koff_delta(int koff) {
    int t9 = koff / 9;
    int r9 = koff - t9 * 9;
    int t3 = r9 / 3;
    return (t9 - 1) * (P * P) + (t3 - 1) * P + (r9 - t3 * 3 - 1);
}

// ---------------- padded bitmap rank structure (uint2 = {word, base}) ----------------

__global__ void build_bitmap_p(const int* __restrict__ coords, int N,
                               uint2* __restrict__ recs) {
    int i = blockIdx.x * blockDim.x + threadIdx.x;
    if (i >= N) return;
    int x = coords[3 * i], y = coords[3 * i + 1], z = coords[3 * i + 2];
    int key = ((x + 1) * P + (y + 1)) * P + (z + 1);
    atomicOr((unsigned int*)&recs[key >> 5], 1u << (key & 31));
}

__global__ __launch_bounds__(256)
void bitmap_count_p(const uint2* __restrict__ recs, int* __restrict__ bcnt) {
    __shared__ int tot[256];
    int b = blockIdx.x, t = threadIdx.x;
    int w0 = b * WPB + t * 4;
    int s = 0;
#pragma unroll
    for (int j = 0; j < 4; j++) {
        int w = w0 + j;
        if (w < NWP) s += __popc(recs[w].x);
    }
    tot[t] = s;
    __syncthreads();
    if (t < 128) tot[t] += tot[t + 128];
    __syncthreads();
    if (t < 64) {
        int v = tot[t] + tot[t + 64];
#pragma unroll
        for (int d = 32; d > 0; d >>= 1) v += __shfl_down(v, d);
        if (t == 0) bcnt[b] = v;
    }
}

// exclusive scan of n<=256 values, one block of 256 threads
__global__ void scan_small(const int* __restrict__ cnt, int* __restrict__ base, int n) {
    __shared__ int tot[256];
    int t = threadIdx.x;
    int v = (t < n) ? cnt[t] : 0;
    tot[t] = v;
    __syncthreads();
    for (int d = 1; d < 256; d <<= 1) {
        int u = (t >= d) ? tot[t - d] : 0;
        __syncthreads();
        tot[t] += u;
        __syncthreads();
    }
    if (t < n) base[t] = tot[t] - v;     // exclusive
}

__global__ __launch_bounds__(256)
void base_fill_p(uint2* __restrict__ recs, const int* __restrict__ bbase) {
    __shared__ int tot[256];
    int b = blockIdx.x, t = threadIdx.x;
    int w0 = b * WPB + t * 4;
    int p[4];
    int s = 0;
#pragma unroll
    for (int j = 0; j < 4; j++) {
        int w = w0 + j;
        p[j] = (w < NWP) ? __popc(recs[w].x) : 0;
        s += p[j];
    }
    tot[t] = s;
    __syncthreads();
    for (int d = 1; d < 256; d <<= 1) {
        int u = (t >= d) ? tot[t - d] : 0;
        __syncthreads();
        tot[t] += u;
        __syncthreads();
    }
    int run = bbase[b] + tot[t] - s;     // exclusive global rank of first word
#pragma unroll
    for (int j = 0; j < 4; j++) {
        int w = w0 + j;
        if (w < NWP) recs[w].y = (uint32_t)run;
        run += p[j];
    }
}

// ---------------- skeys generated COALESCED from the bitmap (sorted order) ----------------

__global__ __launch_bounds__(256)
void gen_skeys(const uint2* __restrict__ recs, int* __restrict__ skeys) {
    int w = blockIdx.x * blockDim.x + threadIdx.x;
    if (w >= NWP) return;
    uint2 rb = recs[w];
    uint32_t m = rb.x;
    int base = (int)rb.y;
    int key0 = w * 32;
    while (m) {
        int bit = __ffs((int)m) - 1;
        skeys[base++] = key0 + bit;
        m &= m - 1u;
    }
}

// ---------------- rank scatter: original order -> sorted order ----------------

__global__ __launch_bounds__(256)
void rank_scatter_p(const int* __restrict__ coords, const float* __restrict__ feat, int N,
                    const uint2* __restrict__ recs,
                    int* __restrict__ sorig,
                    uint4* __restrict__ feat_bf) {
    int i = blockIdx.x * blockDim.x + threadIdx.x;
    if (i >= N) return;
    int x = coords[3 * i], y = coords[3 * i + 1], z = coords[3 * i + 2];
    int key = ((x + 1) * P + (y + 1)) * P + (z + 1);
    uint2 rb = recs[key >> 5];
    int bit = key & 31;
    int r = (int)(rb.y + (uint32_t)__popc(rb.x & ((1u << bit) - 1u)));
    sorig[r] = i;
    const float* fr = feat + (size_t)i * CIN;
    float2 a = *(const float2*)fr;
    float2 bb = *(const float2*)(fr + 2);
    float2 cc = *(const float2*)(fr + 4);
    uint4 u;
    u.x = pack2(a.x, a.y);
    u.y = pack2(bb.x, bb.y);
    u.z = pack2(cc.x, cc.y);
    u.w = 0u;
    feat_bf[r] = u;
}

// ---------------- W fragment prep (once) ----------------
// NEW k-permutation (kb-major): slot (ks, chunk) <-> koff = chunk*7 + ks.
// k = ks*32 + chunk*8 + ci; A gathers the SAME mapping -> dot product invariant.
// B-fragment (16x16x32 bf16): lane l holds B[k = ks*32+(l>>4)*8+b][col = nt*16+(l&15)]

__global__ void prep_wfrag(const float* __restrict__ W, uint4* __restrict__ wfrag) {
    int idx = blockIdx.x * blockDim.x + threadIdx.x;
    if (idx >= 7 * 2 * 64) return;
    int l = idx & 63;
    int nt = (idx >> 6) & 1;
    int ks = idx >> 7;
    int koff = (l >> 4) * 7 + ks;        // kb-major permutation
    int col = nt * 16 + (l & 15);
    unsigned short v[8];
#pragma unroll
    for (int ci = 0; ci < 8; ci++) {
        float f = 0.f;
        if (ci < CIN && koff < NOFF) f = W[(koff * CIN + ci) * COUT + col];
        v[ci] = f2bf(f);
    }
    uint4 u;
    u.x = (uint32_t)v[0] | ((uint32_t)v[1] << 16);
    u.y = (uint32_t)v[2] | ((uint32_t)v[3] << 16);
    u.z = (uint32_t)v[4] | ((uint32_t)v[5] << 16);
    u.w = (uint32_t)v[6] | ((uint32_t)v[7] << 16);
    wfrag[idx] = u;
}

// ---------------- conv: z-clustered rank probes (3 probe loads instead of 7) ----------------
// Thread kb owns koffs kb*7..kb*7+6 = 3 z-contiguous clusters (breaks at b1, b1+3;
// b1 = {3,2,1,3}[kb]). One uint2 record read per cluster + predicated straddle read.
// Pad slot (kb=3, ks=6 -> koff 27) probes K_INV in the zeroed guard -> miss.

__global__ __launch_bounds__(256, 4)
void conv_mfma(const uint4* __restrict__ feat_bf,
               const int* __restrict__ skeys,
               const int* __restrict__ sorig,
               const uint4* __restrict__ wfrag,
               const uint2* __restrict__ recs, int N, int nsb,
               float* __restrict__ out,
               float* __restrict__ stats_g) {
    __shared__ __align__(16) float Clds[64 * 36];    // 9216 B
    __shared__ float bstat[64];

    int tid = threadIdx.x;
    int w = tid >> 6, l = tid & 63;
    int col = l & 15;
    int rg = l >> 4;
    int kb = rg;

    if (tid < 64) bstat[tid] = 0.f;

    // B fragments: loaded ONCE per block
    const short8* wf8 = (const short8*)wfrag;
    short8 bf0[7], bf1[7];
#pragma unroll
    for (int ks = 0; ks < 7; ks++) {
        bf0[ks] = wf8[(ks * 2 + 0) * 64 + l];
        bf1[ks] = wf8[(ks * 2 + 1) * 64 + l];
    }

    // cluster geometry (per-thread constants)
    int b1 = (0x3123 >> (kb * 4)) & 0xF;     // first break slot: {3,2,1,3}[kb]
    int b2 = b1 + 3;                          // second break slot
    int len0 = b1, len2 = 4 - b1;             // len1 = 3
    int koffC0 = kb * 7;
    int koffC1 = koffC0 + b1;
    int koffC2 = koffC0 + b2;                 // ==27 only for kb=3 (pad cluster)
    int d0 = koff_delta(koffC0);
    int d1 = koff_delta(koffC1);
    bool padC2 = (koffC2 >= NOFF);
    int d2 = padC2 ? 0 : koff_delta(koffC2);

    const uint4* fb16 = (const uint4*)feat_bf;

    float as0 = 0.f, aq0 = 0.f, as1 = 0.f, aq1 = 0.f;

    for (int sb = blockIdx.x; sb < nsb; sb += gridDim.x) {
        int b = xcd_swizzle(sb, nsb);
        int bs = b * 64;
        int site = bs + w * 16 + col;
        int key = (site < N) ? skeys[site] : K_INV;

        // cluster probes (one uint2 each, predicated straddle extension)
        int nkA = key + d0;
        int nkB = key + d1;
        int nkC = padC2 ? K_INV : key + d2;
        int waA = nkA >> 5, waB = nkB >> 5, waC = nkC >> 5;
        uint2 rA0 = recs[waA];
        uint2 rB0 = recs[waB];
        uint2 rC0 = recs[waC];
        uint2 rA1 = rA0, rB1 = rB0, rC1 = rC0;
        if (((nkA & 31) + len0) > 32) rA1 = recs[waA + 1];
        if (((nkB & 31) + 3) > 32)    rB1 = recs[waB + 1];
        if (((nkC & 31) + len2) > 32) rC1 = recs[waC + 1];

        // per-slot decode + PREDICATED gathers
        short8 av[7];
#pragma unroll
        for (int ks = 0; ks < 7; ks++) {
            int c = (ks >= b1) + (ks >= b2);
            int nk = (c == 0) ? (nkA + ks)
                   : (c == 1) ? (nkB + (ks - b1))
                              : (nkC + (ks - b2));
            int wa  = (c == 0) ? waA : (c == 1) ? waB : waC;
            uint2 r0 = (c == 0) ? rA0 : (c == 1) ? rB0 : rC0;
            uint2 r1 = (c == 0) ? rA1 : (c == 1) ? rB1 : rC1;
            bool second = (nk >> 5) != wa;
            uint32_t wd = second ? r1.x : r0.x;
            uint32_t bw = second ? r1.y : r0.y;
            int p = nk & 31;
            bool hit = (wd >> p) & 1u;
            uint4 a4 = make_uint4(0u, 0u, 0u, 0u);
            if (hit) {
                int pos = (int)(bw + (uint32_t)__popc(wd & ((1u << p) - 1u)));
                a4 = fb16[pos];
            }
            av[ks] = *(const short8*)&a4;
        }

        f32x4 acc0 = {0.f, 0.f, 0.f, 0.f};
        f32x4 acc1 = {0.f, 0.f, 0.f, 0.f};
#pragma unroll
        for (int ks = 0; ks < 7; ks++) {
            acc0 = __builtin_amdgcn_mfma_f32_16x16x32_bf16(av[ks], bf0[ks], acc0, 0, 0, 0);
            acc1 = __builtin_amdgcn_mfma_f32_16x16x32_bf16(av[ks], bf1[ks], acc1, 0, 0, 0);
        }

        // accumulate stats (invalid sites contribute exact zeros)
        as0 += acc0[0] + acc0[1] + acc0[2] + acc0[3];
        aq0 += acc0[0]*acc0[0] + acc0[1]*acc0[1] + acc0[2]*acc0[2] + acc0[3]*acc0[3];
        as1 += acc1[0] + acc1[1] + acc1[2] + acc1[3];
        aq1 += acc1[0]*acc1[0] + acc1[1]*acc1[1] + acc1[2]*acc1[2] + acc1[3]*acc1[3];

        __syncthreads();                 // prev iteration's Clds reads complete
#pragma unroll
        for (int r = 0; r < 4; r++) {
            int s = w * 16 + rg * 4 + r; // C/D map: col=lane&15, row=(lane>>4)*4+r
            Clds[s * 36 + col] = acc0[r];
            Clds[s * 36 + col + 16] = acc1[r];
        }
        __syncthreads();                 // Clds writes complete

        int st = tid >> 2;               // site-local 0..63
        int q = (tid & 3) * 2;           // chunk pair
        int sr = bs + st;
        if (sr < N) {
            float4* gp = (float4*)(out + (size_t)sorig[sr] * COUT + q * 4);
            gp[0] = *(const float4*)&Clds[st * 36 + q * 4];
            gp[1] = *(const float4*)&Clds[st * 36 + q * 4 + 4];
        }
    }

    // final stats reduction (once per block)
    as0 += __shfl_xor(as0, 16); as0 += __shfl_xor(as0, 32);
    aq0 += __shfl_xor(aq0, 16); aq0 += __shfl_xor(aq0, 32);
    as1 += __shfl_xor(as1, 16); as1 += __shfl_xor(as1, 32);
    aq1 += __shfl_xor(aq1, 16); aq1 += __shfl_xor(aq1, 32);
    __syncthreads();
    if (l < 16) {
        atomicAdd(&bstat[col], as0);
        atomicAdd(&bstat[16 + col], as1);
        atomicAdd(&bstat[32 + col], aq0);
        atomicAdd(&bstat[48 + col], aq1);
    }
    __syncthreads();
    if (tid < 64) {
        int slice = blockIdx.x & 63;
        atomicAdd(&stats_g[slice * 64 + tid], bstat[tid]);
    }
}

// ---------------- BN finalize / norm ----------------

__global__ void finalize_sliced(const float* __restrict__ stats_g,
                                const float* __restrict__ gamma,
                                const float* __restrict__ beta,
                                float invN, float* __restrict__ scsh) {
    int c = threadIdx.x;
    if (c < COUT) {
        float s = 0.f, q = 0.f;
        for (int sl = 0; sl < 64; sl++) {
            s += stats_g[sl * 64 + c];
            q += stats_g[sl * 64 + 32 + c];
        }
        float mean = s * invN;
        float var = q * invN - mean * mean;
        float sc = gamma[c] * rsqrtf(var + BN_EPS);
        scsh[c] = sc;
        scsh[COUT + c] = beta[c] - mean * sc;
    }
}

__global__ __launch_bounds__(256)
void norm_kernel(float* __restrict__ out, long total_vec,
                 const float* __restrict__ scaleshift) {
    __shared__ float sc[COUT], sh[COUT];
    for (int t = threadIdx.x; t < COUT; t += blockDim.x) {
        sc[t] = scaleshift[t];
        sh[t] = scaleshift[COUT + t];
    }
    __syncthreads();
    long stride = (long)gridDim.x * blockDim.x;
    float4* p = (float4*)out;
    for (long v = (long)blockIdx.x * blockDim.x + threadIdx.x; v < total_vec; v += stride) {
        int cbase = (int)(v & 7) * 4;
        float4 u = p[v];
        u.x = fmaxf(u.x * sc[cbase + 0] + sh[cbase + 0], 0.f);
        u.y = fmaxf(u.y * sc[cbase + 1] + sh[cbase + 1], 0.f);
        u.z = fmaxf(u.z * sc[cbase + 2] + sh[cbase + 2], 0.f);
        u.w = fmaxf(u.w * sc[cbase + 3] + sh[cbase + 3], 0.f);
        p[v] = u;
    }
}

// ---------------- launch ----------------

extern "C" void kernel_launch(void* const* d_in, const int* in_sizes, int n_in,
                              void* d_out, int out_size, void* d_ws, size_t ws_size,
                              hipStream_t stream) {
    const float* feat   = (const float*)d_in[0];
    const int*   coords = (const int*)d_in[1];
    const float* W      = (const float*)d_in[2];
    const float* gamma  = (const float*)d_in[3];
    const float* beta   = (const float*)d_in[4];
    float* out = (float*)d_out;

    int N = in_sizes[0] / CIN;
    const int threads = 256;
    int blocksN = (N + threads - 1) / threads;
    int nsb = (N + 63) / 64;
    int cblocks = 1024;                  // R11/R13 empirical optimum
    long total_vec = (long)N * COUT / 4;

    size_t a256 = 255;
    size_t recs_b     = (size_t)NWP * 8;                       // ~2.1 MB
    size_t off_skeys  = (recs_b + a256) & ~a256;
    size_t off_featbf = (off_skeys + (size_t)N * 4 + a256) & ~a256;
    size_t off_sorig  = (off_featbf + (size_t)(N + 1) * 16 + a256) & ~a256;
    size_t off_bcnt   = (off_sorig + (size_t)N * 4 + a256) & ~a256;
    size_t off_bbase  = (off_bcnt + 256 * 4 + a256) & ~a256;
    size_t off_wfrag  = (off_bbase + 256 * 4 + a256) & ~a256;
    size_t off_stats  = (off_wfrag + (size_t)(7 * 2 * 64) * 16 + a256) & ~a256;
    size_t off_scsh   = off_stats + (size_t)64 * 64 * 4;

    uint2* recs  = (uint2*)d_ws;
    int*   skeys = (int*)((char*)d_ws + off_skeys);
    uint4* featb = (uint4*)((char*)d_ws + off_featbf);
    int*   sorig = (int*)((char*)d_ws + off_sorig);
    int*   bcnt  = (int*)((char*)d_ws + off_bcnt);
    int*   bbase = (int*)((char*)d_ws + off_bbase);
    uint4* wfrag = (uint4*)((char*)d_ws + off_wfrag);
    float* stats = (float*)((char*)d_ws + off_stats);
    float* scsh  = (float*)((char*)d_ws + off_scsh);

    hipMemsetAsync(recs, 0, recs_b, stream);
    hipMemsetAsync(stats, 0, (size_t)64 * 64 * 4, stream);
    prep_wfrag<<<4, threads, 0, stream>>>(W, wfrag);
    build_bitmap_p<<<blocksN, threads, 0, stream>>>(coords, N, recs);
    bitmap_count_p<<<NBLKP, threads, 0, stream>>>(recs, bcnt);
    scan_small<<<1, threads, 0, stream>>>(bcnt, bbase, NBLKP);
    base_fill_p<<<NBLKP, threads, 0, stream>>>(recs, bbase);
    gen_skeys<<<(NWP + threads - 1) / threads, threads, 0, stream>>>(recs, skeys);
    rank_scatter_p<<<blocksN, threads, 0, stream>>>(coords, feat, N, recs, sorig, featb);
    conv_mfma<<<cblocks, threads, 0, stream>>>(featb, skeys, sorig, wfrag, recs, N, nsb, out, stats);
    finalize_sliced<<<1, 64, 0, stream>>>(stats, gamma, beta, 1.0f / (float)N, scsh);
    norm_kernel<<<2048, threads, 0, stream>>>(out, total_vec, scsh);
}

// Round 15
// 194.781 us; speedup vs baseline: 1.1917x; 1.0057x over previous
//
#include <hip/hip_runtime.h>
#include <stdint.h>

#define GRIDX 200
#define P 202                                   // padded grid dim
#define PCELL (P * P * P)                       // 8,242,408
#define GUARD 100000
#define NBITS (PCELL + GUARD)
#define NWP ((NBITS + 31) / 32)                 // 260,701 words
#define K_INV (PCELL + 50000)                   // guaranteed-miss key (guard center)
#define CIN 6
#define COUT 32
#define NOFF 27
#define BN_EPS 1e-5f
#define WPB 1024
#define NBLKP ((NWP + WPB - 1) / WPB)           // 255 (<=256 for single-block scan)

typedef __attribute__((ext_vector_type(8))) short short8;
typedef __attribute__((ext_vector_type(4))) float f32x4;

// ---------------- helpers ----------------

__device__ __forceinline__ int xcd_swizzle(int b, int nwg) {
    int q = nwg >> 3, r = nwg & 7;
    int xcd = b & 7, idx = b >> 3;
    int base = (xcd < r) ? xcd * (q + 1) : r * (q + 1) + (xcd - r) * q;
    return base + idx;
}

__device__ __forceinline__ unsigned short f2bf(float f) {
    uint32_t u = __float_as_uint(f);
    return (unsigned short)((u + 0x7FFFu + ((u >> 16) & 1u)) >> 16);   // RNE
}
__device__ __forceinline__ uint32_t pack2(float a, float b) {
    return (uint32_t)f2bf(a) | ((uint32_t)f2bf(b) << 16);
}

// padded-grid key delta for kernel offset koff (0..26)
__device__ __forceinline__ int koff_delta(int koff) {
    int t9 = koff / 9;
    int r9 = koff - t9 * 9;
    int t3 = r9 / 3;
    return (t9 - 1) * (P * P) + (t3 - 1) * P + (r9 - t3 * 3 - 1);
}

// ---------------- padded bitmap rank structure (uint2 = {word, base}) ----------------

// 4 sites/thread: 3 int4 coord loads instead of 12 scalar loads
__global__ __launch_bounds__(256)
void build_bitmap_v4(const int* __restrict__ coords, int N, uint2* __restrict__ recs) {
    int t = blockIdx.x * blockDim.x + threadIdx.x;
    int i0 = t * 4;
    if (i0 >= N) return;
    if (i0 + 4 <= N) {
        const int4* c4 = (const int4*)(coords + (size_t)i0 * 3);
        int4 ca = c4[0], cb = c4[1], cc = c4[2];
        int cx[4] = {ca.x, ca.w, cb.z, cc.y};
        int cy[4] = {ca.y, cb.x, cb.w, cc.z};
        int cz[4] = {ca.z, cb.y, cc.x, cc.w};
#pragma unroll
        for (int s = 0; s < 4; s++) {
            int key = ((cx[s] + 1) * P + (cy[s] + 1)) * P + (cz[s] + 1);
            atomicOr((unsigned int*)&recs[key >> 5], 1u << (key & 31));
        }
    } else {
        for (int i = i0; i < N; i++) {
            int x = coords[3 * i], y = coords[3 * i + 1], z = coords[3 * i + 2];
            int key = ((x + 1) * P + (y + 1)) * P + (z + 1);
            atomicOr((unsigned int*)&recs[key >> 5], 1u << (key & 31));
        }
    }
}

__global__ __launch_bounds__(256)
void bitmap_count_p(const uint2* __restrict__ recs, int* __restrict__ bcnt) {
    __shared__ int tot[256];
    int b = blockIdx.x, t = threadIdx.x;
    int w0 = b * WPB + t * 4;
    int s = 0;
#pragma unroll
    for (int j = 0; j < 4; j++) {
        int w = w0 + j;
        if (w < NWP) s += __popc(recs[w].x);
    }
    tot[t] = s;
    __syncthreads();
    if (t < 128) tot[t] += tot[t + 128];
    __syncthreads();
    if (t < 64) {
        int v = tot[t] + tot[t + 64];
#pragma unroll
        for (int d = 32; d > 0; d >>= 1) v += __shfl_down(v, d);
        if (t == 0) bcnt[b] = v;
    }
}

// exclusive scan of n<=256 values, one block of 256 threads
__global__ void scan_small(const int* __restrict__ cnt, int* __restrict__ base, int n) {
    __shared__ int tot[256];
    int t = threadIdx.x;
    int v = (t < n) ? cnt[t] : 0;
    tot[t] = v;
    __syncthreads();
    for (int d = 1; d < 256; d <<= 1) {
        int u = (t >= d) ? tot[t - d] : 0;
        __syncthreads();
        tot[t] += u;
        __syncthreads();
    }
    if (t < n) base[t] = tot[t] - v;     // exclusive
}

// base_fill with FUSED skeys generation: the word's exclusive rank `run` is in
// hand here, so emit its set-bit keys directly (replaces the gen_skeys pass).
__global__ __launch_bounds__(256)
void base_fill_skeys(uint2* __restrict__ recs, const int* __restrict__ bbase,
                     int* __restrict__ skeys) {
    __shared__ int tot[256];
    int b = blockIdx.x, t = threadIdx.x;
    int w0 = b * WPB + t * 4;
    uint32_t wd[4];
    int p[4];
    int s = 0;
#pragma unroll
    for (int j = 0; j < 4; j++) {
        int w = w0 + j;
        wd[j] = (w < NWP) ? recs[w].x : 0u;
        p[j] = __popc(wd[j]);
        s += p[j];
    }
    tot[t] = s;
    __syncthreads();
    for (int d = 1; d < 256; d <<= 1) {
        int u = (t >= d) ? tot[t - d] : 0;
        __syncthreads();
        tot[t] += u;
        __syncthreads();
    }
    int run = bbase[b] + tot[t] - s;     // exclusive global rank of first word
#pragma unroll
    for (int j = 0; j < 4; j++) {
        int w = w0 + j;
        if (w < NWP) {
            recs[w].y = (uint32_t)run;
            uint32_t m = wd[j];
            int rr = run;
            int k0 = w * 32;
            while (m) {
                int bit = __ffs((int)m) - 1;
                skeys[rr++] = k0 + bit;
                m &= m - 1u;
            }
            run += p[j];
        }
    }
}

// ---------------- rank scatter: 4 sites/thread, vectorized loads ----------------

__global__ __launch_bounds__(256)
void rank_scatter_v4(const int* __restrict__ coords, const float* __restrict__ feat, int N,
                     const uint2* __restrict__ recs,
                     int* __restrict__ sorig, uint4* __restrict__ feat_bf) {
    int t = blockIdx.x * blockDim.x + threadIdx.x;
    int i0 = t * 4;
    if (i0 >= N) return;
    if (i0 + 4 <= N) {
        const int4* c4 = (const int4*)(coords + (size_t)i0 * 3);
        int4 ca = c4[0], cb = c4[1], cc = c4[2];
        int cx[4] = {ca.x, ca.w, cb.z, cc.y};
        int cy[4] = {ca.y, cb.x, cb.w, cc.z};
        int cz[4] = {ca.z, cb.y, cc.x, cc.w};
        const float4* f4 = (const float4*)(feat + (size_t)i0 * 6);
        float4 fa = f4[0], fb = f4[1], fc = f4[2], fd = f4[3], fe = f4[4], ff = f4[5];
        float fs[4][6] = {
            {fa.x, fa.y, fa.z, fa.w, fb.x, fb.y},
            {fb.z, fb.w, fc.x, fc.y, fc.z, fc.w},
            {fd.x, fd.y, fd.z, fd.w, fe.x, fe.y},
            {fe.z, fe.w, ff.x, ff.y, ff.z, ff.w}};
#pragma unroll
        for (int s = 0; s < 4; s++) {
            int key = ((cx[s] + 1) * P + (cy[s] + 1)) * P + (cz[s] + 1);
            uint2 rb = recs[key >> 5];
            int bit = key & 31;
            int r = (int)(rb.y + (uint32_t)__popc(rb.x & ((1u << bit) - 1u)));
            sorig[r] = i0 + s;
            uint4 u;
            u.x = pack2(fs[s][0], fs[s][1]);
            u.y = pack2(fs[s][2], fs[s][3]);
            u.z = pack2(fs[s][4], fs[s][5]);
            u.w = 0u;
            feat_bf[r] = u;
        }
    } else {
        for (int i = i0; i < N; i++) {
            int x = coords[3 * i], y = coords[3 * i + 1], z = coords[3 * i + 2];
            int key = ((x + 1) * P + (y + 1)) * P + (z + 1);
            uint2 rb = recs[key >> 5];
            int bit = key & 31;
            int r = (int)(rb.y + (uint32_t)__popc(rb.x & ((1u << bit) - 1u)));
            sorig[r] = i;
            const float* fr = feat + (size_t)i * CIN;
            uint4 u;
            u.x = pack2(fr[0], fr[1]);
            u.y = pack2(fr[2], fr[3]);
            u.z = pack2(fr[4], fr[5]);
            u.w = 0u;
            feat_bf[r] = u;
        }
    }
}

// ---------------- W fragment prep (once) ----------------
// k-permutation (kb-major): slot (ks, chunk) <-> koff = chunk*7 + ks.
// k = ks*32 + chunk*8 + ci; A gathers the SAME mapping -> dot product invariant.

__global__ void prep_wfrag(const float* __restrict__ W, uint4* __restrict__ wfrag) {
    int idx = blockIdx.x * blockDim.x + threadIdx.x;
    if (idx >= 7 * 2 * 64) return;
    int l = idx & 63;
    int nt = (idx >> 6) & 1;
    int ks = idx >> 7;
    int koff = (l >> 4) * 7 + ks;        // kb-major permutation
    int col = nt * 16 + (l & 15);
    unsigned short v[8];
#pragma unroll
    for (int ci = 0; ci < 8; ci++) {
        float f = 0.f;
        if (ci < CIN && koff < NOFF) f = W[(koff * CIN + ci) * COUT + col];
        v[ci] = f2bf(f);
    }
    uint4 u;
    u.x = (uint32_t)v[0] | ((uint32_t)v[1] << 16);
    u.y = (uint32_t)v[2] | ((uint32_t)v[3] << 16);
    u.z = (uint32_t)v[4] | ((uint32_t)v[5] << 16);
    u.w = (uint32_t)v[6] | ((uint32_t)v[7] << 16);
    wfrag[idx] = u;
}

// ---------------- conv: z-clustered rank probes (R14, validated) ----------------

__global__ __launch_bounds__(256, 4)
void conv_mfma(const uint4* __restrict__ feat_bf,
               const int* __restrict__ skeys,
               const int* __restrict__ sorig,
               const uint4* __restrict__ wfrag,
               const uint2* __restrict__ recs, int N, int nsb,
               float* __restrict__ out,
               float* __restrict__ stats_g) {
    __shared__ __align__(16) float Clds[64 * 36];    // 9216 B
    __shared__ float bstat[64];

    int tid = threadIdx.x;
    int w = tid >> 6, l = tid & 63;
    int col = l & 15;
    int rg = l >> 4;
    int kb = rg;

    if (tid < 64) bstat[tid] = 0.f;

    // B fragments: loaded ONCE per block
    const short8* wf8 = (const short8*)wfrag;
    short8 bf0[7], bf1[7];
#pragma unroll
    for (int ks = 0; ks < 7; ks++) {
        bf0[ks] = wf8[(ks * 2 + 0) * 64 + l];
        bf1[ks] = wf8[(ks * 2 + 1) * 64 + l];
    }

    // cluster geometry (per-thread constants)
    int b1 = (0x3123 >> (kb * 4)) & 0xF;     // first break slot: {3,2,1,3}[kb]
    int b2 = b1 + 3;                          // second break slot
    int len0 = b1, len2 = 4 - b1;             // len1 = 3
    int koffC0 = kb * 7;
    int koffC1 = koffC0 + b1;
    int koffC2 = koffC0 + b2;                 // ==27 only for kb=3 (pad cluster)
    int d0 = koff_delta(koffC0);
    int d1 = koff_delta(koffC1);
    bool padC2 = (koffC2 >= NOFF);
    int d2 = padC2 ? 0 : koff_delta(koffC2);

    const uint4* fb16 = (const uint4*)feat_bf;

    float as0 = 0.f, aq0 = 0.f, as1 = 0.f, aq1 = 0.f;

    for (int sb = blockIdx.x; sb < nsb; sb += gridDim.x) {
        int b = xcd_swizzle(sb, nsb);
        int bs = b * 64;
        int site = bs + w * 16 + col;
        int key = (site < N) ? skeys[site] : K_INV;

        // cluster probes (one uint2 each, predicated straddle extension)
        int nkA = key + d0;
        int nkB = key + d1;
        int nkC = padC2 ? K_INV : key + d2;
        int waA = nkA >> 5, waB = nkB >> 5, waC = nkC >> 5;
        uint2 rA0 = recs[waA];
        uint2 rB0 = recs[waB];
        uint2 rC0 = recs[waC];
        uint2 rA1 = rA0, rB1 = rB0, rC1 = rC0;
        if (((nkA & 31) + len0) > 32) rA1 = recs[waA + 1];
        if (((nkB & 31) + 3) > 32)    rB1 = recs[waB + 1];
        if (((nkC & 31) + len2) > 32) rC1 = recs[waC + 1];

        // per-slot decode + PREDICATED gathers
        short8 av[7];
#pragma unroll
        for (int ks = 0; ks < 7; ks++) {
            int c = (ks >= b1) + (ks >= b2);
            int nk = (c == 0) ? (nkA + ks)
                   : (c == 1) ? (nkB + (ks - b1))
                              : (nkC + (ks - b2));
            int wa  = (c == 0) ? waA : (c == 1) ? waB : waC;
            uint2 r0 = (c == 0) ? rA0 : (c == 1) ? rB0 : rC0;
            uint2 r1 = (c == 0) ? rA1 : (c == 1) ? rB1 : rC1;
            bool second = (nk >> 5) != wa;
            uint32_t wd = second ? r1.x : r0.x;
            uint32_t bw = second ? r1.y : r0.y;
            int p = nk & 31;
            bool hit = (wd >> p) & 1u;
            uint4 a4 = make_uint4(0u, 0u, 0u, 0u);
            if (hit) {
                int pos = (int)(bw + (uint32_t)__popc(wd & ((1u << p) - 1u)));
                a4 = fb16[pos];
            }
            av[ks] = *(const short8*)&a4;
        }

        f32x4 acc0 = {0.f, 0.f, 0.f, 0.f};
        f32x4 acc1 = {0.f, 0.f, 0.f, 0.f};
#pragma unroll
        for (int ks = 0; ks < 7; ks++) {
            acc0 = __builtin_amdgcn_mfma_f32_16x16x32_bf16(av[ks], bf0[ks], acc0, 0, 0, 0);
            acc1 = __builtin_amdgcn_mfma_f32_16x16x32_bf16(av[ks], bf1[ks], acc1, 0, 0, 0);
        }

        // accumulate stats (invalid sites contribute exact zeros)
        as0 += acc0[0] + acc0[1] + acc0[2] + acc0[3];
        aq0 += acc0[0]*acc0[0] + acc0[1]*acc0[1] + acc0[2]*acc0[2] + acc0[3]*acc0[3];
        as1 += acc1[0] + acc1[1] + acc1[2] + acc1[3];
        aq1 += acc1[0]*acc1[0] + acc1[1]*acc1[1] + acc1[2]*acc1[2] + acc1[3]*acc1[3];

        __syncthreads();                 // prev iteration's Clds reads complete
#pragma unroll
        for (int r = 0; r < 4; r++) {
            int s = w * 16 + rg * 4 + r; // C/D map: col=lane&15, row=(lane>>4)*4+r
            Clds[s * 36 + col] = acc0[r];
            Clds[s * 36 + col + 16] = acc1[r];
        }
        __syncthreads();                 // Clds writes complete

        int st = tid >> 2;               // site-local 0..63
        int q = (tid & 3) * 2;           // chunk pair
        int sr = bs + st;
        if (sr < N) {
            float4* gp = (float4*)(out + (size_t)sorig[sr] * COUT + q * 4);
            gp[0] = *(const float4*)&Clds[st * 36 + q * 4];
            gp[1] = *(const float4*)&Clds[st * 36 + q * 4 + 4];
        }
    }

    // final stats reduction (once per block)
    as0 += __shfl_xor(as0, 16); as0 += __shfl_xor(as0, 32);
    aq0 += __shfl_xor(aq0, 16); aq0 += __shfl_xor(aq0, 32);
    as1 += __shfl_xor(as1, 16); as1 += __shfl_xor(as1, 32);
    aq1 += __shfl_xor(aq1, 16); aq1 += __shfl_xor(aq1, 32);
    __syncthreads();
    if (l < 16) {
        atomicAdd(&bstat[col], as0);
        atomicAdd(&bstat[16 + col], as1);
        atomicAdd(&bstat[32 + col], aq0);
        atomicAdd(&bstat[48 + col], aq1);
    }
    __syncthreads();
    if (tid < 64) {
        int slice = blockIdx.x & 63;
        atomicAdd(&stats_g[slice * 64 + tid], bstat[tid]);
    }
}

// ---------------- BN finalize / norm ----------------

__global__ void finalize_sliced(const float* __restrict__ stats_g,
                                const float* __restrict__ gamma,
                                const float* __restrict__ beta,
                                float invN, float* __restrict__ scsh) {
    int c = threadIdx.x;
    if (c < COUT) {
        float s = 0.f, q = 0.f;
        for (int sl = 0; sl < 64; sl++) {
            s += stats_g[sl * 64 + c];
            q += stats_g[sl * 64 + 32 + c];
        }
        float mean = s * invN;
        float var = q * invN - mean * mean;
        float sc = gamma[c] * rsqrtf(var + BN_EPS);
        scsh[c] = sc;
        scsh[COUT + c] = beta[c] - mean * sc;
    }
}

__global__ __launch_bounds__(256)
void norm_kernel(float* __restrict__ out, long total_vec,
                 const float* __restrict__ scaleshift) {
    __shared__ float sc[COUT], sh[COUT];
    for (int t = threadIdx.x; t < COUT; t += blockDim.x) {
        sc[t] = scaleshift[t];
        sh[t] = scaleshift[COUT + t];
    }
    __syncthreads();
    long stride = (long)gridDim.x * blockDim.x;
    float4* p = (float4*)out;
    for (long v = (long)blockIdx.x * blockDim.x + threadIdx.x; v < total_vec; v += stride) {
        int cbase = (int)(v & 7) * 4;
        float4 u = p[v];
        u.x = fmaxf(u.x * sc[cbase + 0] + sh[cbase + 0], 0.f);
        u.y = fmaxf(u.y * sc[cbase + 1] + sh[cbase + 1], 0.f);
        u.z = fmaxf(u.z * sc[cbase + 2] + sh[cbase + 2], 0.f);
        u.w = fmaxf(u.w * sc[cbase + 3] + sh[cbase + 3], 0.f);
        p[v] = u;
    }
}

// ---------------- launch ----------------

extern "C" void kernel_launch(void* const* d_in, const int* in_sizes, int n_in,
                              void* d_out, int out_size, void* d_ws, size_t ws_size,
                              hipStream_t stream) {
    const float* feat   = (const float*)d_in[0];
    const int*   coords = (const int*)d_in[1];
    const float* W      = (const float*)d_in[2];
    const float* gamma  = (const float*)d_in[3];
    const float* beta   = (const float*)d_in[4];
    float* out = (float*)d_out;

    int N = in_sizes[0] / CIN;
    const int threads = 256;
    int blocks4 = (N + 4 * threads - 1) / (4 * threads);   // 4 sites/thread kernels
    int nsb = (N + 63) / 64;
    int cblocks = 1024;                  // R11/R13 empirical optimum
    long total_vec = (long)N * COUT / 4;

    size_t a256 = 255;
    size_t recs_b     = (size_t)NWP * 8;                       // ~2.1 MB
    size_t off_stats  = (recs_b + a256) & ~a256;               // adjacent -> one memset
    size_t zero_bytes = off_stats + (size_t)64 * 64 * 4;
    size_t off_scsh   = (zero_bytes + a256) & ~a256;
    size_t off_skeys  = (off_scsh + 2 * COUT * 4 + a256) & ~a256;
    size_t off_featbf = (off_skeys + (size_t)N * 4 + a256) & ~a256;
    size_t off_sorig  = (off_featbf + (size_t)(N + 1) * 16 + a256) & ~a256;
    size_t off_bcnt   = (off_sorig + (size_t)N * 4 + a256) & ~a256;
    size_t off_bbase  = (off_bcnt + 256 * 4 + a256) & ~a256;
    size_t off_wfrag  = (off_bbase + 256 * 4 + a256) & ~a256;

    uint2* recs  = (uint2*)d_ws;
    float* stats = (float*)((char*)d_ws + off_stats);
    float* scsh  = (float*)((char*)d_ws + off_scsh);
    int*   skeys = (int*)((char*)d_ws + off_skeys);
    uint4* featb = (uint4*)((char*)d_ws + off_featbf);
    int*   sorig = (int*)((char*)d_ws + off_sorig);
    int*   bcnt  = (int*)((char*)d_ws + off_bcnt);
    int*   bbase = (int*)((char*)d_ws + off_bbase);
    uint4* wfrag = (uint4*)((char*)d_ws + off_wfrag);

    hipMemsetAsync(d_ws, 0, zero_bytes, stream);               // recs + stats in one fill
    prep_wfrag<<<4, threads, 0, stream>>>(W, wfrag);
    build_bitmap_v4<<<blocks4, threads, 0, stream>>>(coords, N, recs);
    bitmap_count_p<<<NBLKP, threads, 0, stream>>>(recs, bcnt);
    scan_small<<<1, threads, 0, stream>>>(bcnt, bbase, NBLKP);
    base_fill_skeys<<<NBLKP, threads, 0, stream>>>(recs, bbase, skeys);
    rank_scatter_v4<<<blocks4, threads, 0, stream>>>(coords, feat, N, recs, sorig, featb);
    conv_mfma<<<cblocks, threads, 0, stream>>>(featb, skeys, sorig, wfrag, recs, N, nsb, out, stats);
    finalize_sliced<<<1, 64, 0, stream>>>(stats, gamma, beta, 1.0f / (float)N, scsh);
    norm_kernel<<<2048, threads, 0, stream>>>(out, total_vec, scsh);
}